// Round 12
// baseline (252.515 us; speedup 1.0000x reference)
//
#include <hip/hip_runtime.h>
#include <hip/hip_bf16.h>

// dims: Bk=16, n=256, E=768, G=128, Cout_g=256, Cin_g=192, B=4, K=4, L=16, H=16, D=64
// out = [pooled 16*768][batch 131072*Tmax][valid 4*Tmax]
// ws layout: int ctrl[64] @0 ([0..15] len, [16..31] cum, [32..35] total);
//            Wp u16 @byte 1024  (32 ls x 6 kk x 4096 slots x 8 u16, swizzle-baked)
//            Lp u16 @byte 1024+12582912 (16x256x768 bf16)
// decode: g = ls*4 + beta, d = beta*16 + (o>>4), h = o&15

typedef float f32x4 __attribute__((ext_vector_type(4)));
typedef __bf16 bf16x8 __attribute__((ext_vector_type(8)));
typedef unsigned short u16x4 __attribute__((ext_vector_type(4)));
typedef unsigned short u16x8 __attribute__((ext_vector_type(8)));

__device__ __forceinline__ unsigned short f2bf(float f) {
    union { float f; unsigned u; } v; v.f = f;
    unsigned r = v.u + 0x7FFFu + ((v.u >> 16) & 1u);
    return (unsigned short)(r >> 16);
}

__device__ __forceinline__ bf16x8 ldfrag(const unsigned short* p) {
    u16x8 r = *(const u16x8*)p;
    return __builtin_bit_cast(bf16x8, r);
}

// barrier that waits LDS ops only — lets global-store ACKs float past
__device__ __forceinline__ void bar_lgkm() {
    asm volatile("s_waitcnt lgkmcnt(0)\n\ts_barrier" ::: "memory");
}

// lens + prefix sums + valid flags
__global__ void cums_kernel(const int* __restrict__ mask, int* __restrict__ ws,
                            float* __restrict__ valid_out, int Tmax) {
    int tid = threadIdx.x;
    int w = tid >> 6, lane = tid & 63;
    int m = mask[w * 256 + lane] + mask[w * 256 + lane + 64] +
            mask[w * 256 + lane + 128] + mask[w * 256 + lane + 192];
#pragma unroll
    for (int off = 32; off > 0; off >>= 1) m += __shfl_down(m, off);
    if (lane == 0) ws[w] = m;
    __syncthreads();
    if (tid == 0) {
        for (int b = 0; b < 4; ++b) {
            int c = 0;
            for (int j = 0; j < 4; ++j) { ws[16 + b * 4 + j] = c; c += ws[b * 4 + j]; }
            ws[32 + b] = c;
        }
    }
    __syncthreads();
    for (int i = tid; i < 4 * Tmax; i += 1024) {
        int b = i / Tmax;
        int T = i - b * Tmax;
        valid_out[i] = (T < ws[32 + b]) ? 1.0f : 0.0f;
    }
}

// pooled + fused lh->bf16 pack: block = (bs, e-chunk of 64)
__global__ void pooled_kernel(const float* __restrict__ lh, const int* __restrict__ mask,
                              const int* __restrict__ ws, float* __restrict__ pooled,
                              unsigned short* __restrict__ Lp) {
    int bs = blockIdx.x / 12;
    int ec = blockIdx.x - bs * 12;
    int tid = threadIdx.x;
    int tg = tid >> 6, lane = tid & 63;
    int e = ec * 64 + lane;
    float s = 0.f;
    for (int t = tg; t < 256; t += 4) {
        size_t off = (size_t)(bs * 256 + t) * 768 + e;
        float v = lh[off];
        if (Lp) Lp[off] = f2bf(v);
        s += v * (float)mask[bs * 256 + t];
    }
    __shared__ float red[4][64];
    red[tg][lane] = s;
    __syncthreads();
    if (tg == 0) {
        float tot = red[0][lane] + red[1][lane] + red[2][lane] + red[3][lane];
        pooled[bs * 768 + e] = tot / (float)ws[bs];
    }
}

// zero tail, row-contiguous
__global__ void zerotail_kernel(float* __restrict__ batch, const int* __restrict__ ws,
                                int Tmax) {
    int rr = blockIdx.x;              // 0..2047
    int b = rr >> 9;
    int rem = rr & 511;
    int l = rem >> 5, s = (rem >> 4) & 1, h = rem & 15;
    int total = ws[32 + b];
    int span = Tmax - total;
    if (span <= 0) return;
    float* row = batch + (((size_t)((l * 2 + s) * 4 + b) * 16 + h) * (size_t)Tmax + total) * 64;
    f32x4 z = {0.f, 0.f, 0.f, 0.f};
    int nchunk = span << 4;
    for (int j = threadIdx.x; j < nchunk; j += 256)
        *(f32x4*)(row + (j << 2)) = z;
}

// pack wgt f32 -> bf16, LDS-linear, XOR-swizzle baked.
__global__ void packw_kernel(const float* __restrict__ wgt, unsigned short* __restrict__ Wp) {
    int bid = blockIdx.x;            // 0..3071
    int ls = bid / 96;
    int rem = bid - ls * 96;
    int kk = rem >> 4;
    int blk = rem & 15;
    int slot = (blk << 8) + threadIdx.x;
    int row = slot >> 2;
    int sc = slot & 3;
    int coloff = (sc ^ ((row >> 1) & 3)) << 3;
    const float* src = wgt + (size_t)ls * 196608 + row * 192 + (kk << 5) + coloff;
    f32x4 a0 = *(const f32x4*)src;
    f32x4 a1 = *(const f32x4*)(src + 4);
    u16x8 w = { f2bf(a0[0]), f2bf(a0[1]), f2bf(a0[2]), f2bf(a0[3]),
                f2bf(a1[0]), f2bf(a1[1]), f2bf(a1[2]), f2bf(a1[3]) };
    *(u16x8*)(Wp + (((size_t)(ls * 6 + kk) << 12) + slot) * 8) = w;
}

// All-beta GEMM; A via global_load_lds from pre-packed bf16 (PACKED) or f32 fallback.
// block = (ls, bs, tq): M'=1024 x N=32 t, K=192. 512 thr = 8 waves = beta x oh.
// Epilogue: Ltr transpose + 1KB-burst stores; lgkm-only barriers (stores float).
template<bool PACKED>
__global__ __launch_bounds__(512, 4) void gemm_kernel(
    const float* __restrict__ lh, const float* __restrict__ wgt,
    const unsigned short* __restrict__ Wp, const unsigned short* __restrict__ Lp,
    const float* __restrict__ bias, const int* __restrict__ ws,
    float* __restrict__ out, int Tmax) {
    __shared__ __align__(16) unsigned short As[1024][32];   // 64KB; reused as Ltr f32[128][68]
    __shared__ __align__(16) float biasT[16][68];

    int x = blockIdx.x;
    int xcd = x & 7;
    int rest = x >> 3;
    int lsq = rest >> 7;
    int rb = rest & 127;
    int ls = (lsq << 3) + xcd;      // pinned per XCD
    int bs = rb >> 3;
    int tq = rb & 7;

    int len = ws[bs];
    int tbase = tq << 5;
    if (tbase >= len) return;

    int tid = threadIdx.x;

    // bias -> biasT[h][beta*16+dmid]
    {
        int i0 = tid, i1 = tid + 512;
        biasT[i0 & 15][((i0 >> 8) << 4) + ((i0 & 255) >> 4)] = bias[(ls << 10) + i0];
        biasT[i1 & 15][((i1 >> 8) << 4) + ((i1 & 255) >> 4)] = bias[(ls << 10) + i1];
    }

    int lane = tid & 63;
    int wv = tid >> 6;
    int beta = wv >> 1, oh = wv & 1;
    int p = lane & 15, q = lane >> 4;

    f32x4 acc[8][2] = {};

#pragma unroll
    for (int cc = 0; cc < 6; ++cc) {
        const int kk = cc << 5;
        if constexpr (PACKED) {
            // A: 8 x global_load_lds(16B), zero VALU, LDS-linear (swizzle pre-baked)
            const char* gbase = (const char*)Wp +
                (((size_t)(ls * 6 + cc) << 12) + (wv << 6) + lane) * 16;
            char* lbase = ((char*)&As[0][0]) + ((wv << 6) << 4);
#pragma unroll
            for (int it = 0; it < 8; ++it)
                __builtin_amdgcn_global_load_lds(
                    (const __attribute__((address_space(1))) void*)(gbase + it * 8192),
                    (__attribute__((address_space(3))) void*)(lbase + it * 8192), 16, 0, 0);
        } else {
            const float* Awg = wgt + (size_t)ls * 196608;
            int arow0 = tid >> 2;
            int achk = tid & 3;
#pragma unroll
            for (int it = 0; it < 8; ++it) {
                int row = arow0 + (it << 7);
                const float* src = Awg + row * 192 + kk + (achk << 3);
                f32x4 a0 = *(const f32x4*)src;
                f32x4 a1 = *(const f32x4*)(src + 4);
                u16x8 aw = { f2bf(a0[0]), f2bf(a0[1]), f2bf(a0[2]), f2bf(a0[3]),
                             f2bf(a1[0]), f2bf(a1[1]), f2bf(a1[2]), f2bf(a1[3]) };
                *(u16x8*)&As[row][(achk ^ ((row >> 1) & 3)) << 3] = aw;
            }
        }
        // B fragments for this chunk
        bf16x8 bf[2];
        if constexpr (PACKED) {
            const unsigned short* Brow = Lp + ((size_t)(bs * 256 + tbase + p)) * 768 +
                                         beta * 192 + (q << 3) + kk;
            bf[0] = ldfrag(Brow);
            bf[1] = ldfrag(Brow + 12288);
        } else {
            const float* Brow = lh + (size_t)bs * 196608 + (size_t)(tbase + p) * 768 +
                                beta * 192 + (q << 3) + kk;
#pragma unroll
            for (int n = 0; n < 2; ++n) {
                const float* bp = Brow + n * 16 * 768;
                f32x4 b0 = *(const f32x4*)bp;
                f32x4 b1 = *(const f32x4*)(bp + 4);
                u16x8 bw = { f2bf(b0[0]), f2bf(b0[1]), f2bf(b0[2]), f2bf(b0[3]),
                             f2bf(b1[0]), f2bf(b1[1]), f2bf(b1[2]), f2bf(b1[3]) };
                bf[n] = __builtin_bit_cast(bf16x8, bw);
            }
        }
        __syncthreads();                 // true dependency: gload_lds -> LDS reads
        // MFMA: 8 o-subtiles x 2 t-fragments
#pragma unroll
        for (int r8 = 0; r8 < 8; ++r8) {
            int row = (beta << 8) + (oh << 7) + (r8 << 4) + p;
            bf16x8 af = ldfrag(&As[row][(q ^ ((row >> 1) & 3)) << 3]);
            acc[r8][0] = __builtin_amdgcn_mfma_f32_16x16x32_bf16(af, bf[0], acc[r8][0], 0, 0, 0);
            acc[r8][1] = __builtin_amdgcn_mfma_f32_16x16x32_bf16(af, bf[1], acc[r8][1], 0, 0, 0);
        }
        __syncthreads();                 // vmcnt already 0 here; cheap
    }

    // ---- epilogue: transpose via Ltr f32[128][68]; lgkm-only barriers ----
    float* Ltr = (float*)&As[0][0];
    int cum = ws[16 + bs];
    int b = bs >> 2;
    float* batch = out + 12288;
    size_t hd0 = (size_t)((ls << 2) + b) << 4;

    int toff = lane & 3, dcq = lane >> 2;
    int col0 = (beta << 4) + (oh << 3);

#pragma unroll
    for (int r = 0; r < 4; ++r) {
#pragma unroll
        for (int n = 0; n < 2; ++n) {
            int rowL = (((n << 4) + p) << 2) + q;
            f32x4 v0 = { acc[0][n][r], acc[1][n][r], acc[2][n][r], acc[3][n][r] };
            f32x4 v1 = { acc[4][n][r], acc[5][n][r], acc[6][n][r], acc[7][n][r] };
            *(f32x4*)(Ltr + rowL * 68 + col0) = v0;
            *(f32x4*)(Ltr + rowL * 68 + col0 + 4) = v1;
        }
        bar_lgkm();                      // ds_writes visible; stores keep floating
#pragma unroll
        for (int gi = 0; gi < 4; ++gi) {
            int flat = (wv << 2) + gi;
            int hq = flat >> 3, t4 = flat & 7;
            int tloc = (t4 << 2) + toff;
            int h = (hq << 2) + r;
            int tglob = tbase + tloc;
            f32x4 v = *(const f32x4*)(Ltr + ((tloc << 2) + hq) * 68 + (dcq << 2));
            v += *(const f32x4*)&biasT[h][dcq << 2];
            if (tglob < len) {
                float* dst = batch + ((hd0 + h) * (size_t)Tmax + cum + tglob) * 64;
                *(f32x4*)(dst + (dcq << 2)) = v;
            }
        }
        bar_lgkm();                      // ds_reads done; do NOT drain store ACKs
    }
}

extern "C" void kernel_launch(void* const* d_in, const int* in_sizes, int n_in,
                              void* d_out, int out_size, void* d_ws, size_t ws_size,
                              hipStream_t stream) {
    const float* lh   = (const float*)d_in[0];
    const int*   mask = (const int*)d_in[1];
    const float* wgt  = (const float*)d_in[2];
    const float* bias = (const float*)d_in[3];
    float* out = (float*)d_out;
    int* ws = (int*)d_ws;

    int Tmax = (out_size - 12288) / 131076;

    unsigned short* Wp = (unsigned short*)((char*)d_ws + 1024);
    unsigned short* Lp = (unsigned short*)((char*)d_ws + 1024 + 12582912);
    const size_t need = 1024 + 12582912 + 6291456;
    bool packed = ws_size >= need;

    cums_kernel<<<1, 1024, 0, stream>>>(mask, ws, out + 12288 + (size_t)131072 * Tmax, Tmax);
    pooled_kernel<<<16 * 12, 256, 0, stream>>>(lh, mask, ws, out, packed ? Lp : nullptr);
    zerotail_kernel<<<2048, 256, 0, stream>>>(out + 12288, ws, Tmax);

    if (packed) {
        packw_kernel<<<3072, 256, 0, stream>>>(wgt, Wp);
        gemm_kernel<true><<<4096, 512, 0, stream>>>(nullptr, nullptr, Wp, Lp, bias, ws, out, Tmax);
    } else {
        gemm_kernel<false><<<4096, 512, 0, stream>>>(lh, wgt, nullptr, nullptr, bias, ws, out, Tmax);
    }
}

// Round 13
// 235.764 us; speedup vs baseline: 1.0710x; 1.0710x over previous
//
#include <hip/hip_runtime.h>
#include <hip/hip_bf16.h>

// dims: Bk=16, n=256, E=768, G=128, Cout_g=256, Cin_g=192, B=4, K=4, L=16, H=16, D=64
// out = [pooled 16*768][batch 131072*Tmax][valid 4*Tmax]
// ws layout: int ctrl[64] @0 ([0..15] len, [16..31] cum, [32..35] total);
//            Wp u16 @byte 1024: [ls][kk][1024 rows][32 cols] bf16 (frag-linear, coalesced)
//            Lp u16 @byte 1024+12582912: lh bf16 flat
// decode: g = ls*4 + beta, d = beta*16 + (o>>4), h = o&15

typedef float f32x4 __attribute__((ext_vector_type(4)));
typedef __bf16 bf16x8 __attribute__((ext_vector_type(8)));
typedef unsigned short u16x4 __attribute__((ext_vector_type(4)));
typedef unsigned short u16x8 __attribute__((ext_vector_type(8)));

__device__ __forceinline__ unsigned short f2bf(float f) {
    union { float f; unsigned u; } v; v.f = f;
    unsigned r = v.u + 0x7FFFu + ((v.u >> 16) & 1u);
    return (unsigned short)(r >> 16);
}

__device__ __forceinline__ bf16x8 ldfrag(const unsigned short* p) {
    u16x8 r = *(const u16x8*)p;
    return __builtin_bit_cast(bf16x8, r);
}

__device__ __forceinline__ void bar_lgkm() {
    asm volatile("s_waitcnt lgkmcnt(0)\n\ts_barrier" ::: "memory");
}

// lens + prefix sums + valid flags
__global__ void cums_kernel(const int* __restrict__ mask, int* __restrict__ ws,
                            float* __restrict__ valid_out, int Tmax) {
    int tid = threadIdx.x;
    int w = tid >> 6, lane = tid & 63;
    int m = mask[w * 256 + lane] + mask[w * 256 + lane + 64] +
            mask[w * 256 + lane + 128] + mask[w * 256 + lane + 192];
#pragma unroll
    for (int off = 32; off > 0; off >>= 1) m += __shfl_down(m, off);
    if (lane == 0) ws[w] = m;
    __syncthreads();
    if (tid == 0) {
        for (int b = 0; b < 4; ++b) {
            int c = 0;
            for (int j = 0; j < 4; ++j) { ws[16 + b * 4 + j] = c; c += ws[b * 4 + j]; }
            ws[32 + b] = c;
        }
    }
    __syncthreads();
    for (int i = tid; i < 4 * Tmax; i += 1024) {
        int b = i / Tmax;
        int T = i - b * Tmax;
        valid_out[i] = (T < ws[32 + b]) ? 1.0f : 0.0f;
    }
}

// pooled only (pack NOT fused — scalar bf16 stores were a 20µs regression)
__global__ void pooled_kernel(const float* __restrict__ lh, const int* __restrict__ mask,
                              const int* __restrict__ ws, float* __restrict__ pooled) {
    int bs = blockIdx.x / 12;
    int ec = blockIdx.x - bs * 12;
    int tid = threadIdx.x;
    int tg = tid >> 6, lane = tid & 63;
    int e = ec * 64 + lane;
    float s = 0.f;
    for (int t = tg; t < 256; t += 4) {
        float mf = (float)mask[bs * 256 + t];
        s += lh[(size_t)(bs * 256 + t) * 768 + e] * mf;
    }
    __shared__ float red[4][64];
    red[tg][lane] = s;
    __syncthreads();
    if (tg == 0) {
        float tot = red[0][lane] + red[1][lane] + red[2][lane] + red[3][lane];
        pooled[bs * 768 + e] = tot / (float)ws[bs];
    }
}

// zero tail, row-contiguous
__global__ void zerotail_kernel(float* __restrict__ batch, const int* __restrict__ ws,
                                int Tmax) {
    int rr = blockIdx.x;              // 0..2047
    int b = rr >> 9;
    int rem = rr & 511;
    int l = rem >> 5, s = (rem >> 4) & 1, h = rem & 15;
    int total = ws[32 + b];
    int span = Tmax - total;
    if (span <= 0) return;
    float* row = batch + (((size_t)((l * 2 + s) * 4 + b) * 16 + h) * (size_t)Tmax + total) * 64;
    f32x4 z = {0.f, 0.f, 0.f, 0.f};
    int nchunk = span << 4;
    for (int j = threadIdx.x; j < nchunk; j += 256)
        *(f32x4*)(row + (j << 2)) = z;
}

// pack wgt f32 -> bf16, frag-linear [ls][kk][row][32] (no swizzle needed — no LDS)
__global__ void packw_kernel(const float* __restrict__ wgt, unsigned short* __restrict__ Wp) {
    int bid = blockIdx.x;            // 0..3071
    int ls = bid / 96;
    int rem = bid - ls * 96;
    int kk = rem >> 4;
    int blk = rem & 15;
    int slot = (blk << 8) + threadIdx.x;   // 0..4095
    int row = slot >> 2;
    int sc = slot & 3;
    const float* src = wgt + (size_t)ls * 196608 + row * 192 + (kk << 5) + (sc << 3);
    f32x4 a0 = *(const f32x4*)src;
    f32x4 a1 = *(const f32x4*)(src + 4);
    u16x8 w = { f2bf(a0[0]), f2bf(a0[1]), f2bf(a0[2]), f2bf(a0[3]),
                f2bf(a1[0]), f2bf(a1[1]), f2bf(a1[2]), f2bf(a1[3]) };
    *(u16x8*)(Wp + ((((size_t)(ls * 6 + kk)) << 10) + row) * 32 + (sc << 3)) = w;
}

// pack lh f32 -> bf16 flat (vectorized)
__global__ void packlh_kernel(const float* __restrict__ lh, unsigned short* __restrict__ Lp) {
    size_t slot = (size_t)blockIdx.x * 256 + threadIdx.x;   // < 393216
    const float* src = lh + slot * 8;
    f32x4 a0 = *(const f32x4*)src;
    f32x4 a1 = *(const f32x4*)(src + 4);
    u16x8 w = { f2bf(a0[0]), f2bf(a0[1]), f2bf(a0[2]), f2bf(a0[3]),
                f2bf(a1[0]), f2bf(a1[1]), f2bf(a1[2]), f2bf(a1[3]) };
    *(u16x8*)(Lp + slot * 8) = w;
}

// Barrier-free K-loop GEMM: all operands direct global->register from packed bf16.
// block = (ls, bs, tq): M'=1024 x N=32 t, K=192. 512 thr = 8 waves = beta x oh.
// Wave wv owns A rows [wv*128, wv*128+128); frag load = 16 rows x 64B = 1KB coalesced.
// No LDS, no barriers in the K-loop; TLP (2 blocks/CU) + compiler pipelining hide latency.
// Epilogue: Ltr transpose + 1KB-burst stores (proven clean writes).
__global__ __launch_bounds__(512, 4) void gemm_pk(
    const unsigned short* __restrict__ Wp, const unsigned short* __restrict__ Lp,
    const float* __restrict__ bias, const int* __restrict__ ws,
    float* __restrict__ out, int Tmax) {
    __shared__ __align__(16) float Ltr[128][68];     // 34.8 KB
    __shared__ __align__(16) float biasT[16][68];    // 4.4 KB

    int x = blockIdx.x;
    int xcd = x & 7;
    int rest = x >> 3;
    int lsq = rest >> 7;
    int rb = rest & 127;
    int ls = (lsq << 3) + xcd;      // pinned per XCD
    int bs = rb >> 3;
    int tq = rb & 7;

    int len = ws[bs];
    int tbase = tq << 5;
    if (tbase >= len) return;

    int tid = threadIdx.x;

    // bias -> biasT[h][beta*16+dmid]
    {
        int i0 = tid, i1 = tid + 512;
        biasT[i0 & 15][((i0 >> 8) << 4) + ((i0 & 255) >> 4)] = bias[(ls << 10) + i0];
        biasT[i1 & 15][((i1 >> 8) << 4) + ((i1 & 255) >> 4)] = bias[(ls << 10) + i1];
    }

    int lane = tid & 63;
    int wv = tid >> 6;
    int beta = wv >> 1, oh = wv & 1;
    int p = lane & 15, q = lane >> 4;

    // A: row = wv*128 + r8*16 + p, cols q*8..q*8+8 of chunk cc
    const unsigned short* Ab = Wp + (size_t)ls * 196608 + (wv << 12) + (p << 5) + (q << 3);
    // B: row (tbase + n*16 + p), cols beta*192 + q*8 + cc*32
    const unsigned short* Bb = Lp + ((size_t)(bs * 256 + tbase + p)) * 768 +
                               beta * 192 + (q << 3);

    f32x4 acc[8][2] = {};

#pragma unroll 1
    for (int cc = 0; cc < 6; ++cc) {
        u16x8 ar[8];
#pragma unroll
        for (int r8 = 0; r8 < 8; ++r8)
            ar[r8] = *(const u16x8*)(Ab + (r8 << 9));
        bf16x8 bf0 = ldfrag(Bb);
        bf16x8 bf1 = ldfrag(Bb + 12288);
        __builtin_amdgcn_s_setprio(1);
#pragma unroll
        for (int r8 = 0; r8 < 8; ++r8) {
            bf16x8 af = __builtin_bit_cast(bf16x8, ar[r8]);
            acc[r8][0] = __builtin_amdgcn_mfma_f32_16x16x32_bf16(af, bf0, acc[r8][0], 0, 0, 0);
            acc[r8][1] = __builtin_amdgcn_mfma_f32_16x16x32_bf16(af, bf1, acc[r8][1], 0, 0, 0);
        }
        __builtin_amdgcn_s_setprio(0);
        Ab += 32768;
        Bb += 32;
    }

    // ---- epilogue: transpose via Ltr f32[128][68]; lgkm-only barriers ----
    int cum = ws[16 + bs];
    int b = bs >> 2;
    float* batch = out + 12288;
    size_t hd0 = (size_t)((ls << 2) + b) << 4;

    int toff = lane & 3, dcq = lane >> 2;
    int col0 = (beta << 4) + (oh << 3);

#pragma unroll
    for (int r = 0; r < 4; ++r) {
#pragma unroll
        for (int n = 0; n < 2; ++n) {
            int rowL = (((n << 4) + p) << 2) + q;
            f32x4 v0 = { acc[0][n][r], acc[1][n][r], acc[2][n][r], acc[3][n][r] };
            f32x4 v1 = { acc[4][n][r], acc[5][n][r], acc[6][n][r], acc[7][n][r] };
            *(f32x4*)(&Ltr[rowL][col0]) = v0;
            *(f32x4*)(&Ltr[rowL][col0 + 4]) = v1;
        }
        bar_lgkm();                      // ds_writes visible; stores keep floating
#pragma unroll
        for (int gi = 0; gi < 4; ++gi) {
            int flat = (wv << 2) + gi;
            int hq = flat >> 3, t4 = flat & 7;
            int tloc = (t4 << 2) + toff;
            int h = (hq << 2) + r;
            int tglob = tbase + tloc;
            f32x4 v = *(const f32x4*)(&Ltr[(tloc << 2) + hq][dcq << 2]);
            v += *(const f32x4*)&biasT[h][dcq << 2];
            if (tglob < len) {
                float* dst = batch + ((hd0 + h) * (size_t)Tmax + cum + tglob) * 64;
                *(f32x4*)(dst + (dcq << 2)) = v;
            }
        }
        bar_lgkm();
    }
}

// Fallback (unpacked ws): R10-style LDS staging from f32 inputs.
__global__ __launch_bounds__(512, 4) void gemm_fb(
    const float* __restrict__ lh, const float* __restrict__ wgt,
    const float* __restrict__ bias, const int* __restrict__ ws,
    float* __restrict__ out, int Tmax) {
    __shared__ __align__(16) unsigned short As[1024][32];
    __shared__ __align__(16) float biasT[16][68];

    int x = blockIdx.x;
    int xcd = x & 7;
    int rest = x >> 3;
    int lsq = rest >> 7;
    int rb = rest & 127;
    int ls = (lsq << 3) + xcd;
    int bs = rb >> 3;
    int tq = rb & 7;

    int len = ws[bs];
    int tbase = tq << 5;
    if (tbase >= len) return;

    int tid = threadIdx.x;
    {
        int i0 = tid, i1 = tid + 512;
        biasT[i0 & 15][((i0 >> 8) << 4) + ((i0 & 255) >> 4)] = bias[(ls << 10) + i0];
        biasT[i1 & 15][((i1 >> 8) << 4) + ((i1 & 255) >> 4)] = bias[(ls << 10) + i1];
    }

    int lane = tid & 63;
    int wv = tid >> 6;
    int beta = wv >> 1, oh = wv & 1;
    int p = lane & 15, q = lane >> 4;

    f32x4 acc[8][2] = {};

#pragma unroll
    for (int cc = 0; cc < 6; ++cc) {
        const int kk = cc << 5;
        const float* Awg = wgt + (size_t)ls * 196608;
        int arow0 = tid >> 2;
        int achk = tid & 3;
#pragma unroll
        for (int it = 0; it < 8; ++it) {
            int row = arow0 + (it << 7);
            const float* src = Awg + row * 192 + kk + (achk << 3);
            f32x4 a0 = *(const f32x4*)src;
            f32x4 a1 = *(const f32x4*)(src + 4);
            u16x8 aw = { f2bf(a0[0]), f2bf(a0[1]), f2bf(a0[2]), f2bf(a0[3]),
                         f2bf(a1[0]), f2bf(a1[1]), f2bf(a1[2]), f2bf(a1[3]) };
            *(u16x8*)&As[row][(achk ^ ((row >> 1) & 3)) << 3] = aw;
        }
        bf16x8 bf[2];
        const float* Brow = lh + (size_t)bs * 196608 + (size_t)(tbase + p) * 768 +
                            beta * 192 + (q << 3) + kk;
#pragma unroll
        for (int n = 0; n < 2; ++n) {
            const float* bp = Brow + n * 16 * 768;
            f32x4 b0 = *(const f32x4*)bp;
            f32x4 b1 = *(const f32x4*)(bp + 4);
            u16x8 bw = { f2bf(b0[0]), f2bf(b0[1]), f2bf(b0[2]), f2bf(b0[3]),
                         f2bf(b1[0]), f2bf(b1[1]), f2bf(b1[2]), f2bf(b1[3]) };
            bf[n] = __builtin_bit_cast(bf16x8, bw);
        }
        __syncthreads();
#pragma unroll
        for (int r8 = 0; r8 < 8; ++r8) {
            int row = (beta << 8) + (oh << 7) + (r8 << 4) + p;
            bf16x8 af = ldfrag(&As[row][(q ^ ((row >> 1) & 3)) << 3]);
            acc[r8][0] = __builtin_amdgcn_mfma_f32_16x16x32_bf16(af, bf[0], acc[r8][0], 0, 0, 0);
            acc[r8][1] = __builtin_amdgcn_mfma_f32_16x16x32_bf16(af, bf[1], acc[r8][1], 0, 0, 0);
        }
        __syncthreads();
    }

    float* Ltr = (float*)&As[0][0];
    int cum = ws[16 + bs];
    int b = bs >> 2;
    float* batch = out + 12288;
    size_t hd0 = (size_t)((ls << 2) + b) << 4;

    int toff = lane & 3, dcq = lane >> 2;
    int col0 = (beta << 4) + (oh << 3);

#pragma unroll
    for (int r = 0; r < 4; ++r) {
#pragma unroll
        for (int n = 0; n < 2; ++n) {
            int rowL = (((n << 4) + p) << 2) + q;
            f32x4 v0 = { acc[0][n][r], acc[1][n][r], acc[2][n][r], acc[3][n][r] };
            f32x4 v1 = { acc[4][n][r], acc[5][n][r], acc[6][n][r], acc[7][n][r] };
            *(f32x4*)(Ltr + rowL * 68 + col0) = v0;
            *(f32x4*)(Ltr + rowL * 68 + col0 + 4) = v1;
        }
        __syncthreads();
#pragma unroll
        for (int gi = 0; gi < 4; ++gi) {
            int flat = (wv << 2) + gi;
            int hq = flat >> 3, t4 = flat & 7;
            int tloc = (t4 << 2) + toff;
            int h = (hq << 2) + r;
            int tglob = tbase + tloc;
            f32x4 v = *(const f32x4*)(Ltr + ((tloc << 2) + hq) * 68 + (dcq << 2));
            v += *(const f32x4*)&biasT[h][dcq << 2];
            if (tglob < len) {
                float* dst = batch + ((hd0 + h) * (size_t)Tmax + cum + tglob) * 64;
                *(f32x4*)(dst + (dcq << 2)) = v;
            }
        }
        __syncthreads();
    }
}

extern "C" void kernel_launch(void* const* d_in, const int* in_sizes, int n_in,
                              void* d_out, int out_size, void* d_ws, size_t ws_size,
                              hipStream_t stream) {
    const float* lh   = (const float*)d_in[0];
    const int*   mask = (const int*)d_in[1];
    const float* wgt  = (const float*)d_in[2];
    const float* bias = (const float*)d_in[3];
    float* out = (float*)d_out;
    int* ws = (int*)d_ws;

    int Tmax = (out_size - 12288) / 131076;

    unsigned short* Wp = (unsigned short*)((char*)d_ws + 1024);
    unsigned short* Lp = (unsigned short*)((char*)d_ws + 1024 + 12582912);
    const size_t need = 1024 + 12582912 + 6291456;
    bool packed = ws_size >= need;

    cums_kernel<<<1, 1024, 0, stream>>>(mask, ws, out + 12288 + (size_t)131072 * Tmax, Tmax);
    pooled_kernel<<<16 * 12, 256, 0, stream>>>(lh, mask, ws, out);
    zerotail_kernel<<<2048, 256, 0, stream>>>(out + 12288, ws, Tmax);

    if (packed) {
        packw_kernel<<<3072, 256, 0, stream>>>(wgt, Wp);
        packlh_kernel<<<1536, 256, 0, stream>>>(lh, Lp);
        gemm_pk<<<4096, 512, 0, stream>>>(Wp, Lp, bias, ws, out, Tmax);
    } else {
        gemm_fb<<<4096, 512, 0, stream>>>(lh, wgt, bias, ws, out, Tmax);
    }
}

// Round 14
// 204.294 us; speedup vs baseline: 1.2360x; 1.1540x over previous
//
#include <hip/hip_runtime.h>
#include <hip/hip_bf16.h>

// dims: Bk=16, n=256, E=768, G=128, Cout_g=256, Cin_g=192, B=4, K=4, L=16, H=16, D=64
// out = [pooled 16*768][batch 131072*Tmax][valid 4*Tmax]
// ws layout: int ctrl[64] @0 ([0..15] len, [16..31] cum, [32..35] total);
//            Wp u16 @byte 1024: [ls][kk][4096 slots][8] bf16, LDS-linear w/ XOR swizzle baked
//            Lp u16 @byte 1024+12582912: lh bf16 flat
// decode: g = ls*4 + beta, d = beta*16 + (o>>4), h = o&15

typedef float f32x4 __attribute__((ext_vector_type(4)));
typedef __bf16 bf16x8 __attribute__((ext_vector_type(8)));
typedef unsigned short u16x4 __attribute__((ext_vector_type(4)));
typedef unsigned short u16x8 __attribute__((ext_vector_type(8)));

__device__ __forceinline__ unsigned short f2bf(float f) {
    union { float f; unsigned u; } v; v.f = f;
    unsigned r = v.u + 0x7FFFu + ((v.u >> 16) & 1u);
    return (unsigned short)(r >> 16);
}

__device__ __forceinline__ bf16x8 ldfrag(const unsigned short* p) {
    u16x8 r = *(const u16x8*)p;
    return __builtin_bit_cast(bf16x8, r);
}

// lens + prefix sums + valid flags
__global__ void cums_kernel(const int* __restrict__ mask, int* __restrict__ ws,
                            float* __restrict__ valid_out, int Tmax) {
    int tid = threadIdx.x;
    int w = tid >> 6, lane = tid & 63;
    int m = mask[w * 256 + lane] + mask[w * 256 + lane + 64] +
            mask[w * 256 + lane + 128] + mask[w * 256 + lane + 192];
#pragma unroll
    for (int off = 32; off > 0; off >>= 1) m += __shfl_down(m, off);
    if (lane == 0) ws[w] = m;
    __syncthreads();
    if (tid == 0) {
        for (int b = 0; b < 4; ++b) {
            int c = 0;
            for (int j = 0; j < 4; ++j) { ws[16 + b * 4 + j] = c; c += ws[b * 4 + j]; }
            ws[32 + b] = c;
        }
    }
    __syncthreads();
    for (int i = tid; i < 4 * Tmax; i += 1024) {
        int b = i / Tmax;
        int T = i - b * Tmax;
        valid_out[i] = (T < ws[32 + b]) ? 1.0f : 0.0f;
    }
}

// pooled
__global__ void pooled_kernel(const float* __restrict__ lh, const int* __restrict__ mask,
                              const int* __restrict__ ws, float* __restrict__ pooled) {
    int bs = blockIdx.x / 12;
    int ec = blockIdx.x - bs * 12;
    int tid = threadIdx.x;
    int tg = tid >> 6, lane = tid & 63;
    int e = ec * 64 + lane;
    float s = 0.f;
    for (int t = tg; t < 256; t += 4) {
        float mf = (float)mask[bs * 256 + t];
        s += lh[(size_t)(bs * 256 + t) * 768 + e] * mf;
    }
    __shared__ float red[4][64];
    red[tg][lane] = s;
    __syncthreads();
    if (tg == 0) {
        float tot = red[0][lane] + red[1][lane] + red[2][lane] + red[3][lane];
        pooled[bs * 768 + e] = tot / (float)ws[bs];
    }
}

// merged pack: bid<3072 -> wgt pack (LDS-linear + XOR swizzle baked); else lh pack flat
__global__ void packall_kernel(const float* __restrict__ wgt, const float* __restrict__ lh,
                               unsigned short* __restrict__ Wp, unsigned short* __restrict__ Lp) {
    int bid = blockIdx.x;
    if (bid < 3072) {
        int ls = bid / 96;
        int rem = bid - ls * 96;
        int kk = rem >> 4;
        int blk = rem & 15;
        int slot = (blk << 8) + threadIdx.x;
        int row = slot >> 2;
        int sc = slot & 3;
        int coloff = (sc ^ ((row >> 1) & 3)) << 3;
        const float* src = wgt + (size_t)ls * 196608 + row * 192 + (kk << 5) + coloff;
        f32x4 a0 = *(const f32x4*)src;
        f32x4 a1 = *(const f32x4*)(src + 4);
        u16x8 w = { f2bf(a0[0]), f2bf(a0[1]), f2bf(a0[2]), f2bf(a0[3]),
                    f2bf(a1[0]), f2bf(a1[1]), f2bf(a1[2]), f2bf(a1[3]) };
        *(u16x8*)(Wp + (((size_t)(ls * 6 + kk) << 12) + slot) * 8) = w;
    } else {
        size_t slot = (size_t)(bid - 3072) * 256 + threadIdx.x;   // < 393216
        const float* src = lh + slot * 8;
        f32x4 a0 = *(const f32x4*)src;
        f32x4 a1 = *(const f32x4*)(src + 4);
        u16x8 w = { f2bf(a0[0]), f2bf(a0[1]), f2bf(a0[2]), f2bf(a0[3]),
                    f2bf(a1[0]), f2bf(a1[1]), f2bf(a1[2]), f2bf(a1[3]) };
        *(u16x8*)(Lp + slot * 8) = w;
    }
}

// T-space all-beta GEMM with fused tail-zero. block = (ls, b, Tt): covers output
// T in [Tt*32, Tt*32+32) for all 16 h x 64 d of (ls,b). K-loop/staging = R10 (proven).
// B rows decoded per-lane from cum table; lanes past total[b] contribute zeros.
__global__ __launch_bounds__(512, 4) void gemm_t(
    const unsigned short* __restrict__ Wp, const unsigned short* __restrict__ Lp,
    const float* __restrict__ bias, const int* __restrict__ ws,
    float* __restrict__ out, int Tmax, int nT) {
    __shared__ __align__(16) unsigned short As[1024][32];   // 64KB; reused as Ltr f32[128][68]
    __shared__ __align__(16) float biasT[16][64];           // 4KB

    int x = blockIdx.x;
    int xcd = x & 7;
    int rest = x >> 3;
    int per = nT << 2;
    int lsq = rest / per;
    int j = rest - lsq * per;
    int ls = (lsq << 3) + xcd;      // pinned per XCD
    int b = j / nT;
    int Tt = j - b * nT;
    int Tbase = Tt << 5;

    int total = ws[32 + b];
    int tid = threadIdx.x;
    int lane = tid & 63;
    int wv = tid >> 6;
    int toff = lane & 3, dcq = lane >> 2;
    float* batch = out + 12288;
    size_t hd0 = (size_t)((ls << 2) + b) << 4;

    // fully-tail block: pure zero-store, no GEMM
    if (Tbase >= total) {
        f32x4 z = {0.f, 0.f, 0.f, 0.f};
#pragma unroll
        for (int r = 0; r < 4; ++r) {
#pragma unroll
            for (int gi = 0; gi < 4; ++gi) {
                int flat = (wv << 2) + gi;
                int hq = flat >> 3, t4 = flat & 7;
                int tglob = Tbase + (t4 << 2) + toff;
                int h = (hq << 2) + r;
                if (tglob < Tmax) {
                    float* dst = batch + ((hd0 + h) * (size_t)Tmax + tglob) * 64;
                    *(f32x4*)(dst + (dcq << 2)) = z;
                }
            }
        }
        return;
    }

    // bias -> biasT[h][beta*16+dmid]
    {
        int i0 = tid, i1 = tid + 512;
        biasT[i0 & 15][((i0 >> 8) << 4) + ((i0 & 255) >> 4)] = bias[(ls << 10) + i0];
        biasT[i1 & 15][((i1 >> 8) << 4) + ((i1 & 255) >> 4)] = bias[(ls << 10) + i1];
    }

    int beta = wv >> 1, oh = wv & 1;
    int p = lane & 15, q = lane >> 4;

    // per-lane B row decode (once): Ti(n) = Tbase + n*16 + p
    int c1 = ws[16 + (b << 2) + 1];
    int c2 = ws[16 + (b << 2) + 2];
    int c3 = ws[16 + (b << 2) + 3];
    const unsigned short* Brow[2];
    bool bval[2];
#pragma unroll
    for (int n = 0; n < 2; ++n) {
        int Ti = Tbase + (n << 4) + p;
        bval[n] = Ti < total;
        int TiC = bval[n] ? Ti : (total - 1);
        int sj = (TiC >= c1) + (TiC >= c2) + (TiC >= c3);
        int cum = sj == 0 ? 0 : (sj == 1 ? c1 : (sj == 2 ? c2 : c3));
        int row = ((b << 2) + sj) * 256 + (TiC - cum);
        Brow[n] = Lp + (size_t)row * 768 + beta * 192 + (q << 3);
    }

    f32x4 acc[8][2] = {};
    const bf16x8 bz = {};

#pragma unroll
    for (int cc = 0; cc < 6; ++cc) {
        // A: 8 x global_load_lds(16B), LDS-linear (swizzle pre-baked)  [R10 core]
        const char* gbase = (const char*)Wp +
            (((size_t)(ls * 6 + cc) << 12) + (wv << 6) + lane) * 16;
        char* lbase = ((char*)&As[0][0]) + ((wv << 6) << 4);
#pragma unroll
        for (int it = 0; it < 8; ++it)
            __builtin_amdgcn_global_load_lds(
                (const __attribute__((address_space(1))) void*)(gbase + it * 8192),
                (__attribute__((address_space(3))) void*)(lbase + it * 8192), 16, 0, 0);
        // B fragments (per-lane rows, zeroed past total)
        bf16x8 bf0 = bval[0] ? ldfrag(Brow[0] + (cc << 5)) : bz;
        bf16x8 bf1 = bval[1] ? ldfrag(Brow[1] + (cc << 5)) : bz;
        __syncthreads();
#pragma unroll
        for (int r8 = 0; r8 < 8; ++r8) {
            int row = (beta << 8) + (oh << 7) + (r8 << 4) + p;
            bf16x8 af = ldfrag(&As[row][(q ^ ((row >> 1) & 3)) << 3]);
            acc[r8][0] = __builtin_amdgcn_mfma_f32_16x16x32_bf16(af, bf0, acc[r8][0], 0, 0, 0);
            acc[r8][1] = __builtin_amdgcn_mfma_f32_16x16x32_bf16(af, bf1, acc[r8][1], 0, 0, 0);
        }
        __syncthreads();
    }

    // ---- epilogue: transpose via Ltr f32[128][68], 1KB-burst stores, tail zeros ----
    float* Ltr = (float*)&As[0][0];
    int col0 = (beta << 4) + (oh << 3);

#pragma unroll
    for (int r = 0; r < 4; ++r) {
#pragma unroll
        for (int n = 0; n < 2; ++n) {
            int rowL = (((n << 4) + p) << 2) + q;
            f32x4 v0 = { acc[0][n][r], acc[1][n][r], acc[2][n][r], acc[3][n][r] };
            f32x4 v1 = { acc[4][n][r], acc[5][n][r], acc[6][n][r], acc[7][n][r] };
            *(f32x4*)(Ltr + rowL * 68 + col0) = v0;
            *(f32x4*)(Ltr + rowL * 68 + col0 + 4) = v1;
        }
        __syncthreads();
#pragma unroll
        for (int gi = 0; gi < 4; ++gi) {
            int flat = (wv << 2) + gi;
            int hq = flat >> 3, t4 = flat & 7;
            int tloc = (t4 << 2) + toff;
            int h = (hq << 2) + r;
            int tglob = Tbase + tloc;
            if (tglob < Tmax) {
                f32x4 v;
                if (tglob < total) {
                    v = *(const f32x4*)(Ltr + ((tloc << 2) + hq) * 68 + (dcq << 2));
                    v += *(const f32x4*)&biasT[h][dcq << 2];
                } else {
                    v = (f32x4){0.f, 0.f, 0.f, 0.f};
                }
                float* dst = batch + ((hd0 + h) * (size_t)Tmax + tglob) * 64;
                *(f32x4*)(dst + (dcq << 2)) = v;
            }
        }
        __syncthreads();
    }
}

// Fallback (ws too small): R13 gemm_fb + explicit zerotail
__global__ void zerotail_kernel(float* __restrict__ batch, const int* __restrict__ ws,
                                int Tmax) {
    int rr = blockIdx.x;
    int b = rr >> 9;
    int rem = rr & 511;
    int l = rem >> 5, s = (rem >> 4) & 1, h = rem & 15;
    int total = ws[32 + b];
    int span = Tmax - total;
    if (span <= 0) return;
    float* row = batch + (((size_t)((l * 2 + s) * 4 + b) * 16 + h) * (size_t)Tmax + total) * 64;
    f32x4 z = {0.f, 0.f, 0.f, 0.f};
    int nchunk = span << 4;
    for (int j = threadIdx.x; j < nchunk; j += 256)
        *(f32x4*)(row + (j << 2)) = z;
}

__global__ __launch_bounds__(512, 4) void gemm_fb(
    const float* __restrict__ lh, const float* __restrict__ wgt,
    const float* __restrict__ bias, const int* __restrict__ ws,
    float* __restrict__ out, int Tmax) {
    __shared__ __align__(16) unsigned short As[1024][32];
    __shared__ __align__(16) float biasT[16][64];

    int x = blockIdx.x;
    int xcd = x & 7;
    int rest = x >> 3;
    int lsq = rest >> 7;
    int rb = rest & 127;
    int ls = (lsq << 3) + xcd;
    int bs = rb >> 3;
    int tq = rb & 7;

    int len = ws[bs];
    int tbase = tq << 5;
    if (tbase >= len) return;

    int tid = threadIdx.x;
    {
        int i0 = tid, i1 = tid + 512;
        biasT[i0 & 15][((i0 >> 8) << 4) + ((i0 & 255) >> 4)] = bias[(ls << 10) + i0];
        biasT[i1 & 15][((i1 >> 8) << 4) + ((i1 & 255) >> 4)] = bias[(ls << 10) + i1];
    }

    int lane = tid & 63;
    int wv = tid >> 6;
    int beta = wv >> 1, oh = wv & 1;
    int p = lane & 15, q = lane >> 4;

    f32x4 acc[8][2] = {};

#pragma unroll
    for (int cc = 0; cc < 6; ++cc) {
        const int kk = cc << 5;
        const float* Awg = wgt + (size_t)ls * 196608;
        int arow0 = tid >> 2;
        int achk = tid & 3;
#pragma unroll
        for (int it = 0; it < 8; ++it) {
            int row = arow0 + (it << 7);
            const float* src = Awg + row * 192 + kk + (achk << 3);
            f32x4 a0 = *(const f32x4*)src;
            f32x4 a1 = *(const f32x4*)(src + 4);
            u16x8 aw = { f2bf(a0[0]), f2bf(a0[1]), f2bf(a0[2]), f2bf(a0[3]),
                         f2bf(a1[0]), f2bf(a1[1]), f2bf(a1[2]), f2bf(a1[3]) };
            *(u16x8*)&As[row][(achk ^ ((row >> 1) & 3)) << 3] = aw;
        }
        bf16x8 bf[2];
        const float* Brow = lh + (size_t)bs * 196608 + (size_t)(tbase + p) * 768 +
                            beta * 192 + (q << 3) + kk;
#pragma unroll
        for (int n = 0; n < 2; ++n) {
            const float* bp = Brow + n * 16 * 768;
            f32x4 b0 = *(const f32x4*)bp;
            f32x4 b1 = *(const f32x4*)(bp + 4);
            u16x8 bw = { f2bf(b0[0]), f2bf(b0[1]), f2bf(b0[2]), f2bf(b0[3]),
                         f2bf(b1[0]), f2bf(b1[1]), f2bf(b1[2]), f2bf(b1[3]) };
            bf[n] = __builtin_bit_cast(bf16x8, bw);
        }
        __syncthreads();
#pragma unroll
        for (int r8 = 0; r8 < 8; ++r8) {
            int row = (beta << 8) + (oh << 7) + (r8 << 4) + p;
            bf16x8 af = ldfrag(&As[row][(q ^ ((row >> 1) & 3)) << 3]);
            acc[r8][0] = __builtin_amdgcn_mfma_f32_16x16x32_bf16(af, bf[0], acc[r8][0], 0, 0, 0);
            acc[r8][1] = __builtin_amdgcn_mfma_f32_16x16x32_bf16(af, bf[1], acc[r8][1], 0, 0, 0);
        }
        __syncthreads();
    }

    float* Ltr = (float*)&As[0][0];
    int cum = ws[16 + bs];
    int b = bs >> 2;
    float* batch = out + 12288;
    size_t hd0 = (size_t)((ls << 2) + b) << 4;

    int toff = lane & 3, dcq = lane >> 2;
    int col0 = (beta << 4) + (oh << 3);

#pragma unroll
    for (int r = 0; r < 4; ++r) {
#pragma unroll
        for (int n = 0; n < 2; ++n) {
            int rowL = (((n << 4) + p) << 2) + q;
            f32x4 v0 = { acc[0][n][r], acc[1][n][r], acc[2][n][r], acc[3][n][r] };
            f32x4 v1 = { acc[4][n][r], acc[5][n][r], acc[6][n][r], acc[7][n][r] };
            *(f32x4*)(Ltr + rowL * 68 + col0) = v0;
            *(f32x4*)(Ltr + rowL * 68 + col0 + 4) = v1;
        }
        __syncthreads();
#pragma unroll
        for (int gi = 0; gi < 4; ++gi) {
            int flat = (wv << 2) + gi;
            int hq = flat >> 3, t4 = flat & 7;
            int tloc = (t4 << 2) + toff;
            int h = (hq << 2) + r;
            int tglob = tbase + tloc;
            f32x4 v = *(const f32x4*)(Ltr + ((tloc << 2) + hq) * 68 + (dcq << 2));
            v += *(const f32x4*)&biasT[h][dcq << 2];
            if (tglob < len) {
                float* dst = batch + ((hd0 + h) * (size_t)Tmax + cum + tglob) * 64;
                *(f32x4*)(dst + (dcq << 2)) = v;
            }
        }
        __syncthreads();
    }
}

extern "C" void kernel_launch(void* const* d_in, const int* in_sizes, int n_in,
                              void* d_out, int out_size, void* d_ws, size_t ws_size,
                              hipStream_t stream) {
    const float* lh   = (const float*)d_in[0];
    const int*   mask = (const int*)d_in[1];
    const float* wgt  = (const float*)d_in[2];
    const float* bias = (const float*)d_in[3];
    float* out = (float*)d_out;
    int* ws = (int*)d_ws;

    int Tmax = (out_size - 12288) / 131076;
    int nT = (Tmax + 31) >> 5;

    unsigned short* Wp = (unsigned short*)((char*)d_ws + 1024);
    unsigned short* Lp = (unsigned short*)((char*)d_ws + 1024 + 12582912);
    const size_t need = 1024 + 12582912 + 6291456;
    bool packed = ws_size >= need;

    cums_kernel<<<1, 1024, 0, stream>>>(mask, ws, out + 12288 + (size_t)131072 * Tmax, Tmax);
    pooled_kernel<<<16 * 12, 256, 0, stream>>>(lh, mask, ws, out);

    if (packed) {
        packall_kernel<<<4608, 256, 0, stream>>>(wgt, lh, Wp, Lp);
        gemm_t<<<128 * nT, 512, 0, stream>>>(Wp, Lp, bias, ws, out, Tmax, nT);
    } else {
        zerotail_kernel<<<2048, 256, 0, stream>>>(out + 12288, ws, Tmax);
        gemm_fb<<<4096, 512, 0, stream>>>(lh, wgt, bias, ws, out, Tmax);
    }
}

// Round 15
// 192.417 us; speedup vs baseline: 1.3123x; 1.0617x over previous
//
#include <hip/hip_runtime.h>
#include <hip/hip_bf16.h>

// dims: Bk=16, n=256, E=768, G=128, Cout_g=256, Cin_g=192, B=4, K=4, L=16, H=16, D=64
// out = [pooled 16*768][batch 131072*Tmax][valid 4*Tmax]
// ws layout: int ctrl[64] @0 ([0..15] len, [16..31] cum, [32..35] total);
//            Wp u16 @byte 1024: [ls][kk] 64KB panels, LDS-linear w/ XOR swizzle baked
//            Lp u16 @byte 1024+12582912: lh bf16 flat
// decode: g = ls*4 + beta, d = beta*16 + (o>>4), h = o&15

typedef float f32x4 __attribute__((ext_vector_type(4)));
typedef __bf16 bf16x8 __attribute__((ext_vector_type(8)));
typedef unsigned short u16x4 __attribute__((ext_vector_type(4)));
typedef unsigned short u16x8 __attribute__((ext_vector_type(8)));

__device__ __forceinline__ unsigned short f2bf(float f) {
    union { float f; unsigned u; } v; v.f = f;
    unsigned r = v.u + 0x7FFFu + ((v.u >> 16) & 1u);
    return (unsigned short)(r >> 16);
}

__device__ __forceinline__ bf16x8 ldfrag(const unsigned short* p) {
    u16x8 r = *(const u16x8*)p;
    return __builtin_bit_cast(bf16x8, r);
}

// lens + prefix sums + valid flags
__global__ void cums_kernel(const int* __restrict__ mask, int* __restrict__ ws,
                            float* __restrict__ valid_out, int Tmax) {
    int tid = threadIdx.x;
    int w = tid >> 6, lane = tid & 63;
    int m = mask[w * 256 + lane] + mask[w * 256 + lane + 64] +
            mask[w * 256 + lane + 128] + mask[w * 256 + lane + 192];
#pragma unroll
    for (int off = 32; off > 0; off >>= 1) m += __shfl_down(m, off);
    if (lane == 0) ws[w] = m;
    __syncthreads();
    if (tid == 0) {
        for (int b = 0; b < 4; ++b) {
            int c = 0;
            for (int j = 0; j < 4; ++j) { ws[16 + b * 4 + j] = c; c += ws[b * 4 + j]; }
            ws[32 + b] = c;
        }
    }
    __syncthreads();
    for (int i = tid; i < 4 * Tmax; i += 1024) {
        int b = i / Tmax;
        int T = i - b * Tmax;
        valid_out[i] = (T < ws[32 + b]) ? 1.0f : 0.0f;
    }
}

// pooled
__global__ void pooled_kernel(const float* __restrict__ lh, const int* __restrict__ mask,
                              const int* __restrict__ ws, float* __restrict__ pooled) {
    int bs = blockIdx.x / 12;
    int ec = blockIdx.x - bs * 12;
    int tid = threadIdx.x;
    int tg = tid >> 6, lane = tid & 63;
    int e = ec * 64 + lane;
    float s = 0.f;
    for (int t = tg; t < 256; t += 4) {
        float mf = (float)mask[bs * 256 + t];
        s += lh[(size_t)(bs * 256 + t) * 768 + e] * mf;
    }
    __shared__ float red[4][64];
    red[tg][lane] = s;
    __syncthreads();
    if (tg == 0) {
        float tot = red[0][lane] + red[1][lane] + red[2][lane] + red[3][lane];
        pooled[bs * 768 + e] = tot / (float)ws[bs];
    }
}

// merged pack: bid<3072 -> wgt pack (LDS-linear + XOR swizzle baked); else lh pack flat
__global__ void packall_kernel(const float* __restrict__ wgt, const float* __restrict__ lh,
                               unsigned short* __restrict__ Wp, unsigned short* __restrict__ Lp) {
    int bid = blockIdx.x;
    if (bid < 3072) {
        int ls = bid / 96;
        int rem = bid - ls * 96;
        int kk = rem >> 4;
        int blk = rem & 15;
        int slot = (blk << 8) + threadIdx.x;
        int row = slot >> 2;
        int sc = slot & 3;
        int coloff = (sc ^ ((row >> 1) & 3)) << 3;
        const float* src = wgt + (size_t)ls * 196608 + row * 192 + (kk << 5) + coloff;
        f32x4 a0 = *(const f32x4*)src;
        f32x4 a1 = *(const f32x4*)(src + 4);
        u16x8 w = { f2bf(a0[0]), f2bf(a0[1]), f2bf(a0[2]), f2bf(a0[3]),
                    f2bf(a1[0]), f2bf(a1[1]), f2bf(a1[2]), f2bf(a1[3]) };
        *(u16x8*)(Wp + (((size_t)(ls * 6 + kk) << 12) + slot) * 8) = w;
    } else {
        size_t slot = (size_t)(bid - 3072) * 256 + threadIdx.x;   // < 393216
        const float* src = lh + slot * 8;
        f32x4 a0 = *(const f32x4*)src;
        f32x4 a1 = *(const f32x4*)(src + 4);
        u16x8 w = { f2bf(a0[0]), f2bf(a0[1]), f2bf(a0[2]), f2bf(a0[3]),
                    f2bf(a1[0]), f2bf(a1[1]), f2bf(a1[2]), f2bf(a1[3]) };
        *(u16x8*)(Lp + slot * 8) = w;
    }
}

// T-space all-beta GEMM, barrier-free K-loop (wave-private staging + wave-local vmcnt).
// block = (ls, b, Tt). Wave wv stages ONLY its own 8KB As region (rows wv*128..+128)
// via global_load_lds, waits its own vmcnt(0), MFMAs — no block barriers until epilogue.
__global__ __launch_bounds__(512, 4) void gemm_t(
    const unsigned short* __restrict__ Wp, const unsigned short* __restrict__ Lp,
    const float* __restrict__ bias, const int* __restrict__ ws,
    float* __restrict__ out, int Tmax, int nT) {
    __shared__ __align__(16) unsigned short As[1024][32];   // 64KB; reused as Ltr f32[128][68]
    __shared__ __align__(16) float biasT[16][64];           // 4KB

    int x = blockIdx.x;
    int xcd = x & 7;
    int rest = x >> 3;
    int per = nT << 2;
    int lsq = rest / per;
    int j = rest - lsq * per;
    int ls = (lsq << 3) + xcd;      // pinned per XCD
    int b = j / nT;
    int Tt = j - b * nT;
    int Tbase = Tt << 5;

    int total = ws[32 + b];
    int tid = threadIdx.x;
    int lane = tid & 63;
    int wv = tid >> 6;
    int toff = lane & 3, dcq = lane >> 2;
    float* batch = out + 12288;
    size_t hd0 = (size_t)((ls << 2) + b) << 4;

    // fully-tail block: pure zero-store, no GEMM
    if (Tbase >= total) {
        f32x4 z = {0.f, 0.f, 0.f, 0.f};
#pragma unroll
        for (int r = 0; r < 4; ++r) {
#pragma unroll
            for (int gi = 0; gi < 4; ++gi) {
                int flat = (wv << 2) + gi;
                int hq = flat >> 3, t4 = flat & 7;
                int tglob = Tbase + (t4 << 2) + toff;
                int h = (hq << 2) + r;
                if (tglob < Tmax) {
                    float* dst = batch + ((hd0 + h) * (size_t)Tmax + tglob) * 64;
                    *(f32x4*)(dst + (dcq << 2)) = z;
                }
            }
        }
        return;
    }

    // bias -> biasT[h][beta*16+dmid]
    {
        int i0 = tid, i1 = tid + 512;
        biasT[i0 & 15][((i0 >> 8) << 4) + ((i0 & 255) >> 4)] = bias[(ls << 10) + i0];
        biasT[i1 & 15][((i1 >> 8) << 4) + ((i1 & 255) >> 4)] = bias[(ls << 10) + i1];
    }

    int beta = wv >> 1, oh = wv & 1;
    int p = lane & 15, q = lane >> 4;

    // per-lane B row decode (once): Ti(n) = Tbase + n*16 + p
    int c1 = ws[16 + (b << 2) + 1];
    int c2 = ws[16 + (b << 2) + 2];
    int c3 = ws[16 + (b << 2) + 3];
    const unsigned short* Brow[2];
    bool bval[2];
#pragma unroll
    for (int n = 0; n < 2; ++n) {
        int Ti = Tbase + (n << 4) + p;
        bval[n] = Ti < total;
        int TiC = bval[n] ? Ti : (total - 1);
        int sj = (TiC >= c1) + (TiC >= c2) + (TiC >= c3);
        int cum = sj == 0 ? 0 : (sj == 1 ? c1 : (sj == 2 ? c2 : c3));
        int row = ((b << 2) + sj) * 256 + (TiC - cum);
        Brow[n] = Lp + (size_t)row * 768 + beta * 192 + (q << 3);
    }

    f32x4 acc[8][2] = {};
    const bf16x8 bz = {};

    // wave-private staging: LDS bytes [wv*8192, +8192) <- Wp panel same bytes (identity)
    const char* gpanel = (const char*)Wp + (((size_t)(ls * 6)) << 16) + (wv << 13) + (lane << 4);
    char* lbase = ((char*)&As[0][0]) + (wv << 13);

#pragma unroll
    for (int cc = 0; cc < 6; ++cc) {
        // my ds_reads of previous chunk have completed (data in regs) before overwrite
        asm volatile("s_waitcnt lgkmcnt(0)" ::: "memory");
        __builtin_amdgcn_sched_barrier(0);
        const char* g = gpanel + ((size_t)cc << 16);
#pragma unroll
        for (int it = 0; it < 8; ++it)
            __builtin_amdgcn_global_load_lds(
                (const __attribute__((address_space(1))) void*)(g + it * 1024),
                (__attribute__((address_space(3))) void*)(lbase + it * 1024), 16, 0, 0);
        // B fragments (normal VGPR loads, also covered by the vmcnt wait)
        bf16x8 bf0 = bval[0] ? ldfrag(Brow[0] + (cc << 5)) : bz;
        bf16x8 bf1 = bval[1] ? ldfrag(Brow[1] + (cc << 5)) : bz;
        asm volatile("s_waitcnt vmcnt(0)" ::: "memory");   // wave-local: my A in LDS, my B in regs
        __builtin_amdgcn_sched_barrier(0);
#pragma unroll
        for (int r8 = 0; r8 < 8; ++r8) {
            int row = (wv << 7) + (r8 << 4) + p;
            bf16x8 af = ldfrag(&As[row][(q ^ ((row >> 1) & 3)) << 3]);
            acc[r8][0] = __builtin_amdgcn_mfma_f32_16x16x32_bf16(af, bf0, acc[r8][0], 0, 0, 0);
            acc[r8][1] = __builtin_amdgcn_mfma_f32_16x16x32_bf16(af, bf1, acc[r8][1], 0, 0, 0);
        }
    }

    __syncthreads();   // all waves done with As before Ltr reuse; biasT visible

    // ---- epilogue: transpose via Ltr f32[128][68], 1KB-burst stores, tail zeros ----
    float* Ltr = (float*)&As[0][0];
    int col0 = (beta << 4) + (oh << 3);

#pragma unroll
    for (int r = 0; r < 4; ++r) {
#pragma unroll
        for (int n = 0; n < 2; ++n) {
            int rowL = (((n << 4) + p) << 2) + q;
            f32x4 v0 = { acc[0][n][r], acc[1][n][r], acc[2][n][r], acc[3][n][r] };
            f32x4 v1 = { acc[4][n][r], acc[5][n][r], acc[6][n][r], acc[7][n][r] };
            *(f32x4*)(Ltr + rowL * 68 + col0) = v0;
            *(f32x4*)(Ltr + rowL * 68 + col0 + 4) = v1;
        }
        __syncthreads();
#pragma unroll
        for (int gi = 0; gi < 4; ++gi) {
            int flat = (wv << 2) + gi;
            int hq = flat >> 3, t4 = flat & 7;
            int tloc = (t4 << 2) + toff;
            int h = (hq << 2) + r;
            int tglob = Tbase + tloc;
            if (tglob < Tmax) {
                f32x4 v;
                if (tglob < total) {
                    v = *(const f32x4*)(Ltr + ((tloc << 2) + hq) * 68 + (dcq << 2));
                    v += *(const f32x4*)&biasT[h][dcq << 2];
                } else {
                    v = (f32x4){0.f, 0.f, 0.f, 0.f};
                }
                float* dst = batch + ((hd0 + h) * (size_t)Tmax + tglob) * 64;
                *(f32x4*)(dst + (dcq << 2)) = v;
            }
        }
        __syncthreads();
    }
}

// Fallback (ws too small): barrier-synced LDS staging from f32 + explicit zerotail
__global__ void zerotail_kernel(float* __restrict__ batch, const int* __restrict__ ws,
                                int Tmax) {
    int rr = blockIdx.x;
    int b = rr >> 9;
    int rem = rr & 511;
    int l = rem >> 5, s = (rem >> 4) & 1, h = rem & 15;
    int total = ws[32 + b];
    int span = Tmax - total;
    if (span <= 0) return;
    float* row = batch + (((size_t)((l * 2 + s) * 4 + b) * 16 + h) * (size_t)Tmax + total) * 64;
    f32x4 z = {0.f, 0.f, 0.f, 0.f};
    int nchunk = span << 4;
    for (int j = threadIdx.x; j < nchunk; j += 256)
        *(f32x4*)(row + (j << 2)) = z;
}

__global__ __launch_bounds__(512, 4) void gemm_fb(
    const float* __restrict__ lh, const float* __restrict__ wgt,
    const float* __restrict__ bias, const int* __restrict__ ws,
    float* __restrict__ out, int Tmax) {
    __shared__ __align__(16) unsigned short As[1024][32];
    __shared__ __align__(16) float biasT[16][64];

    int x = blockIdx.x;
    int xcd = x & 7;
    int rest = x >> 3;
    int lsq = rest >> 7;
    int rb = rest & 127;
    int ls = (lsq << 3) + xcd;
    int bs = rb >> 3;
    int tq = rb & 7;

    int len = ws[bs];
    int tbase = tq << 5;
    if (tbase >= len) return;

    int tid = threadIdx.x;
    {
        int i0 = tid, i1 = tid + 512;
        biasT[i0 & 15][((i0 >> 8) << 4) + ((i0 & 255) >> 4)] = bias[(ls << 10) + i0];
        biasT[i1 & 15][((i1 >> 8) << 4) + ((i1 & 255) >> 4)] = bias[(ls << 10) + i1];
    }

    int lane = tid & 63;
    int wv = tid >> 6;
    int beta = wv >> 1, oh = wv & 1;
    int p = lane & 15, q = lane >> 4;

    f32x4 acc[8][2] = {};

#pragma unroll
    for (int cc = 0; cc < 6; ++cc) {
        const int kk = cc << 5;
        const float* Awg = wgt + (size_t)ls * 196608;
        int arow0 = tid >> 2;
        int achk = tid & 3;
#pragma unroll
        for (int it = 0; it < 8; ++it) {
            int row = arow0 + (it << 7);
            const float* src = Awg + row * 192 + kk + (achk << 3);
            f32x4 a0 = *(const f32x4*)src;
            f32x4 a1 = *(const f32x4*)(src + 4);
            u16x8 aw = { f2bf(a0[0]), f2bf(a0[1]), f2bf(a0[2]), f2bf(a0[3]),
                         f2bf(a1[0]), f2bf(a1[1]), f2bf(a1[2]), f2bf(a1[3]) };
            *(u16x8*)&As[row][(achk ^ ((row >> 1) & 3)) << 3] = aw;
        }
        bf16x8 bf[2];
        const float* Brow = lh + (size_t)bs * 196608 + (size_t)(tbase + p) * 768 +
                            beta * 192 + (q << 3) + kk;
#pragma unroll
        for (int n = 0; n < 2; ++n) {
            const float* bp = Brow + n * 16 * 768;
            f32x4 b0 = *(const f32x4*)bp;
            f32x4 b1 = *(const f32x4*)(bp + 4);
            u16x8 bw = { f2bf(b0[0]), f2bf(b0[1]), f2bf(b0[2]), f2bf(b0[3]),
                         f2bf(b1[0]), f2bf(b1[1]), f2bf(b1[2]), f2bf(b1[3]) };
            bf[n] = __builtin_bit_cast(bf16x8, bw);
        }
        __syncthreads();
#pragma unroll
        for (int r8 = 0; r8 < 8; ++r8) {
            int row = (beta << 8) + (oh << 7) + (r8 << 4) + p;
            bf16x8 af = ldfrag(&As[row][(q ^ ((row >> 1) & 3)) << 3]);
            acc[r8][0] = __builtin_amdgcn_mfma_f32_16x16x32_bf16(af, bf[0], acc[r8][0], 0, 0, 0);
            acc[r8][1] = __builtin_amdgcn_mfma_f32_16x16x32_bf16(af, bf[1], acc[r8][1], 0, 0, 0);
        }
        __syncthreads();
    }

    float* Ltr = (float*)&As[0][0];
    int cum = ws[16 + bs];
    int b = bs >> 2;
    float* batch = out + 12288;
    size_t hd0 = (size_t)((ls << 2) + b) << 4;

    int toff = lane & 3, dcq = lane >> 2;
    int col0 = (beta << 4) + (oh << 3);

#pragma unroll
    for (int r = 0; r < 4; ++r) {
#pragma unroll
        for (int n = 0; n < 2; ++n) {
            int rowL = (((n << 4) + p) << 2) + q;
            f32x4 v0 = { acc[0][n][r], acc[1][n][r], acc[2][n][r], acc[3][n][r] };
            f32x4 v1 = { acc[4][n][r], acc[5][n][r], acc[6][n][r], acc[7][n][r] };
            *(f32x4*)(Ltr + rowL * 68 + col0) = v0;
            *(f32x4*)(Ltr + rowL * 68 + col0 + 4) = v1;
        }
        __syncthreads();
#pragma unroll
        for (int gi = 0; gi < 4; ++gi) {
            int flat = (wv << 2) + gi;
            int hq = flat >> 3, t4 = flat & 7;
            int tloc = (t4 << 2) + toff;
            int h = (hq << 2) + r;
            int tglob = tbase + tloc;
            f32x4 v = *(const f32x4*)(Ltr + ((tloc << 2) + hq) * 68 + (dcq << 2));
            v += *(const f32x4*)&biasT[h][dcq << 2];
            if (tglob < len) {
                float* dst = batch + ((hd0 + h) * (size_t)Tmax + cum + tglob) * 64;
                *(f32x4*)(dst + (dcq << 2)) = v;
            }
        }
        __syncthreads();
    }
}

extern "C" void kernel_launch(void* const* d_in, const int* in_sizes, int n_in,
                              void* d_out, int out_size, void* d_ws, size_t ws_size,
                              hipStream_t stream) {
    const float* lh   = (const float*)d_in[0];
    const int*   mask = (const int*)d_in[1];
    const float* wgt  = (const float*)d_in[2];
    const float* bias = (const float*)d_in[3];
    float* out = (float*)d_out;
    int* ws = (int*)d_ws;

    int Tmax = (out_size - 12288) / 131076;
    int nT = (Tmax + 31) >> 5;

    unsigned short* Wp = (unsigned short*)((char*)d_ws + 1024);
    unsigned short* Lp = (unsigned short*)((char*)d_ws + 1024 + 12582912);
    const size_t need = 1024 + 12582912 + 6291456;
    bool packed = ws_size >= need;

    cums_kernel<<<1, 1024, 0, stream>>>(mask, ws, out + 12288 + (size_t)131072 * Tmax, Tmax);
    pooled_kernel<<<16 * 12, 256, 0, stream>>>(lh, mask, ws, out);

    if (packed) {
        packall_kernel<<<4608, 256, 0, stream>>>(wgt, lh, Wp, Lp);
        gemm_t<<<128 * nT, 512, 0, stream>>>(Wp, Lp, bias, ws, out, Tmax, nT);
    } else {
        zerotail_kernel<<<2048, 256, 0, stream>>>(out + 12288, ws, Tmax);
        gemm_fb<<<4096, 512, 0, stream>>>(lh, wgt, bias, ws, out, Tmax);
    }
}

// Round 16
// 187.365 us; speedup vs baseline: 1.3477x; 1.0270x over previous
//
#include <hip/hip_runtime.h>
#include <hip/hip_bf16.h>

// dims: Bk=16, n=256, E=768, G=128, Cout_g=256, Cin_g=192, B=4, K=4, L=16, H=16, D=64
// out = [pooled 16*768][batch 131072*Tmax][valid 4*Tmax]
// ws layout: int ctrl[64] @0 ([0..15] len, [16..31] cum, [32..35] total);
//            Wp u16 @byte 1024: [ls][kk] 64KB panels, LDS-linear w/ XOR swizzle baked
//            Lp u16 @byte 1024+12582912: lh bf16 flat
// decode: g = ls*4 + beta, d = beta*16 + (o>>4), h = o&15

typedef float f32x4 __attribute__((ext_vector_type(4)));
typedef __bf16 bf16x8 __attribute__((ext_vector_type(8)));
typedef unsigned short u16x4 __attribute__((ext_vector_type(4)));
typedef unsigned short u16x8 __attribute__((ext_vector_type(8)));

__device__ __forceinline__ unsigned short f2bf(float f) {
    union { float f; unsigned u; } v; v.f = f;
    unsigned r = v.u + 0x7FFFu + ((v.u >> 16) & 1u);
    return (unsigned short)(r >> 16);
}

__device__ __forceinline__ bf16x8 ldfrag(const unsigned short* p) {
    u16x8 r = *(const u16x8*)p;
    return __builtin_bit_cast(bf16x8, r);
}

// unconditional load + per-lane zero select (keeps vmcnt issue count exec-independent)
__device__ __forceinline__ bf16x8 ldfrag_masked(const unsigned short* p, bool valid) {
    u16x8 r = *(const u16x8*)p;
    u16x8 z = {};
    r = valid ? r : z;
    return __builtin_bit_cast(bf16x8, r);
}

// ---- merged prep: [0,3072) wgt pack | [3072,4608) lh pack | [4608,4800) pooled | 4800 cums ----
__global__ void prep_kernel(const float* __restrict__ wgt, const float* __restrict__ lh,
                            const int* __restrict__ mask,
                            unsigned short* __restrict__ Wp, unsigned short* __restrict__ Lp,
                            int* __restrict__ ws, float* __restrict__ pooled,
                            float* __restrict__ valid_out, int Tmax) {
    __shared__ float red[4][64];
    __shared__ float mred[4];
    int bid = blockIdx.x;
    int tid = threadIdx.x;

    if (bid < 3072) {
        int ls = bid / 96;
        int rem = bid - ls * 96;
        int kk = rem >> 4;
        int blk = rem & 15;
        int slot = (blk << 8) + tid;
        int row = slot >> 2;
        int sc = slot & 3;
        int coloff = (sc ^ ((row >> 1) & 3)) << 3;
        const float* src = wgt + (size_t)ls * 196608 + row * 192 + (kk << 5) + coloff;
        f32x4 a0 = *(const f32x4*)src;
        f32x4 a1 = *(const f32x4*)(src + 4);
        u16x8 w = { f2bf(a0[0]), f2bf(a0[1]), f2bf(a0[2]), f2bf(a0[3]),
                    f2bf(a1[0]), f2bf(a1[1]), f2bf(a1[2]), f2bf(a1[3]) };
        *(u16x8*)(Wp + (((size_t)(ls * 6 + kk) << 12) + slot) * 8) = w;
    } else if (bid < 4608) {
        size_t slot = (size_t)(bid - 3072) * 256 + tid;   // < 393216
        const float* src = lh + slot * 8;
        f32x4 a0 = *(const f32x4*)src;
        f32x4 a1 = *(const f32x4*)(src + 4);
        u16x8 w = { f2bf(a0[0]), f2bf(a0[1]), f2bf(a0[2]), f2bf(a0[3]),
                    f2bf(a1[0]), f2bf(a1[1]), f2bf(a1[2]), f2bf(a1[3]) };
        *(u16x8*)(Lp + slot * 8) = w;
    } else if (bid < 4800) {
        // pooled, self-contained (computes its own mask-sum)
        int r = bid - 4608;            // 0..191
        int bs = r / 12, ec = r - bs * 12;
        int tg = tid >> 6, lane = tid & 63;
        int e = ec * 64 + lane;
        float s = 0.f, mc = 0.f;
        for (int t = tg; t < 256; t += 4) {
            float mf = (float)mask[bs * 256 + t];
            s += lh[(size_t)(bs * 256 + t) * 768 + e] * mf;
            mc += mf;
        }
        red[tg][lane] = s;
        if (lane == 0) mred[tg] = mc;
        __syncthreads();
        if (tg == 0) {
            float tot = red[0][lane] + red[1][lane] + red[2][lane] + red[3][lane];
            float len = mred[0] + mred[1] + mred[2] + mred[3];
            pooled[bs * 768 + e] = tot / len;
        }
    } else {
        // cums: lens, prefix sums, valid flags
        int w = tid >> 6, lane = tid & 63;
        for (int bs = w; bs < 16; bs += 4) {
            int m = mask[bs * 256 + lane] + mask[bs * 256 + lane + 64] +
                    mask[bs * 256 + lane + 128] + mask[bs * 256 + lane + 192];
#pragma unroll
            for (int off = 32; off > 0; off >>= 1) m += __shfl_down(m, off);
            if (lane == 0) ws[bs] = m;
        }
        __syncthreads();
        if (tid == 0) {
            for (int b = 0; b < 4; ++b) {
                int c = 0;
                for (int j = 0; j < 4; ++j) { ws[16 + b * 4 + j] = c; c += ws[b * 4 + j]; }
                ws[32 + b] = c;
            }
        }
        __syncthreads();
        for (int i = tid; i < 4 * Tmax; i += 256) {
            int b = i / Tmax;
            int T = i - b * Tmax;
            valid_out[i] = (T < ws[32 + b]) ? 1.0f : 0.0f;
        }
    }
}

// T-space all-beta GEMM, barrier-free K-loop, wave-private staging,
// B pipelined one chunk ahead with counted vmcnt(2).
__global__ __launch_bounds__(512, 4) void gemm_t(
    const unsigned short* __restrict__ Wp, const unsigned short* __restrict__ Lp,
    const float* __restrict__ bias, const int* __restrict__ ws,
    float* __restrict__ out, int Tmax, int nT) {
    __shared__ __align__(16) unsigned short As[1024][32];   // 64KB; reused as Ltr f32[128][68]
    __shared__ __align__(16) float biasT[16][64];           // 4KB

    int x = blockIdx.x;
    int xcd = x & 7;
    int rest = x >> 3;
    int per = nT << 2;
    int lsq = rest / per;
    int j = rest - lsq * per;
    int ls = (lsq << 3) + xcd;      // pinned per XCD
    int b = j / nT;
    int Tt = j - b * nT;
    int Tbase = Tt << 5;

    int total = ws[32 + b];
    int tid = threadIdx.x;
    int lane = tid & 63;
    int wv = tid >> 6;
    int toff = lane & 3, dcq = lane >> 2;
    float* batch = out + 12288;
    size_t hd0 = (size_t)((ls << 2) + b) << 4;

    // fully-tail block: pure zero-store, no GEMM
    if (Tbase >= total) {
        f32x4 z = {0.f, 0.f, 0.f, 0.f};
#pragma unroll
        for (int r = 0; r < 4; ++r) {
#pragma unroll
            for (int gi = 0; gi < 4; ++gi) {
                int flat = (wv << 2) + gi;
                int hq = flat >> 3, t4 = flat & 7;
                int tglob = Tbase + (t4 << 2) + toff;
                int h = (hq << 2) + r;
                if (tglob < Tmax) {
                    float* dst = batch + ((hd0 + h) * (size_t)Tmax + tglob) * 64;
                    *(f32x4*)(dst + (dcq << 2)) = z;
                }
            }
        }
        return;
    }

    // issue A(0) as early as possible (wave-private region)
    const char* gpanel = (const char*)Wp + (((size_t)(ls * 6)) << 16) + (wv << 13) + (lane << 4);
    char* lbase = ((char*)&As[0][0]) + (wv << 13);
#pragma unroll
    for (int it = 0; it < 8; ++it)
        __builtin_amdgcn_global_load_lds(
            (const __attribute__((address_space(1))) void*)(gpanel + it * 1024),
            (__attribute__((address_space(3))) void*)(lbase + it * 1024), 16, 0, 0);

    // bias -> biasT[h][beta*16+dmid]
    {
        int i0 = tid, i1 = tid + 512;
        biasT[i0 & 15][((i0 >> 8) << 4) + ((i0 & 255) >> 4)] = bias[(ls << 10) + i0];
        biasT[i1 & 15][((i1 >> 8) << 4) + ((i1 & 255) >> 4)] = bias[(ls << 10) + i1];
    }

    int beta = wv >> 1, oh = wv & 1;
    int p = lane & 15, q = lane >> 4;

    // per-lane B row decode (clamped -> addresses always valid)
    int c1 = ws[16 + (b << 2) + 1];
    int c2 = ws[16 + (b << 2) + 2];
    int c3 = ws[16 + (b << 2) + 3];
    const unsigned short* Brow[2];
    bool bval[2];
#pragma unroll
    for (int n = 0; n < 2; ++n) {
        int Ti = Tbase + (n << 4) + p;
        bval[n] = Ti < total;
        int TiC = bval[n] ? Ti : (total - 1);
        int sj = (TiC >= c1) + (TiC >= c2) + (TiC >= c3);
        int cum = sj == 0 ? 0 : (sj == 1 ? c1 : (sj == 2 ? c2 : c3));
        int row = ((b << 2) + sj) * 256 + (TiC - cum);
        Brow[n] = Lp + (size_t)row * 768 + beta * 192 + (q << 3);
    }

    f32x4 acc[8][2] = {};
    const bf16x8 bz = {};

    bf16x8 bc0 = ldfrag_masked(Brow[0], bval[0]);
    bf16x8 bc1 = ldfrag_masked(Brow[1], bval[1]);

#pragma unroll
    for (int cc = 0; cc < 6; ++cc) {
        bf16x8 bn0 = bz, bn1 = bz;
        if (cc < 5) {
            bn0 = ldfrag_masked(Brow[0] + ((cc + 1) << 5), bval[0]);
            bn1 = ldfrag_masked(Brow[1] + ((cc + 1) << 5), bval[1]);
            asm volatile("s_waitcnt vmcnt(2)" ::: "memory");   // A(cc)+B(cc) done; B(cc+1) in flight
        } else {
            asm volatile("s_waitcnt vmcnt(0)" ::: "memory");
        }
        __builtin_amdgcn_sched_barrier(0);
#pragma unroll
        for (int r8 = 0; r8 < 8; ++r8) {
            int row = (wv << 7) + (r8 << 4) + p;
            bf16x8 af = ldfrag(&As[row][(q ^ ((row >> 1) & 3)) << 3]);
            acc[r8][0] = __builtin_amdgcn_mfma_f32_16x16x32_bf16(af, bc0, acc[r8][0], 0, 0, 0);
            acc[r8][1] = __builtin_amdgcn_mfma_f32_16x16x32_bf16(af, bc1, acc[r8][1], 0, 0, 0);
        }
        if (cc < 5) {
            asm volatile("s_waitcnt lgkmcnt(0)" ::: "memory");  // frag reads done -> region reusable
            __builtin_amdgcn_sched_barrier(0);
            const char* g = gpanel + ((size_t)(cc + 1) << 16);
#pragma unroll
            for (int it = 0; it < 8; ++it)
                __builtin_amdgcn_global_load_lds(
                    (const __attribute__((address_space(1))) void*)(g + it * 1024),
                    (__attribute__((address_space(3))) void*)(lbase + it * 1024), 16, 0, 0);
        }
        bc0 = bn0; bc1 = bn1;
    }

    __syncthreads();   // all waves done with As before Ltr reuse; biasT visible

    // ---- epilogue: transpose via Ltr f32[128][68], 1KB-burst stores, tail zeros ----
    float* Ltr = (float*)&As[0][0];
    int col0 = (beta << 4) + (oh << 3);

#pragma unroll
    for (int r = 0; r < 4; ++r) {
#pragma unroll
        for (int n = 0; n < 2; ++n) {
            int rowL = (((n << 4) + p) << 2) + q;
            f32x4 v0 = { acc[0][n][r], acc[1][n][r], acc[2][n][r], acc[3][n][r] };
            f32x4 v1 = { acc[4][n][r], acc[5][n][r], acc[6][n][r], acc[7][n][r] };
            *(f32x4*)(Ltr + rowL * 68 + col0) = v0;
            *(f32x4*)(Ltr + rowL * 68 + col0 + 4) = v1;
        }
        __syncthreads();
#pragma unroll
        for (int gi = 0; gi < 4; ++gi) {
            int flat = (wv << 2) + gi;
            int hq = flat >> 3, t4 = flat & 7;
            int tloc = (t4 << 2) + toff;
            int h = (hq << 2) + r;
            int tglob = Tbase + tloc;
            if (tglob < Tmax) {
                f32x4 v;
                if (tglob < total) {
                    v = *(const f32x4*)(Ltr + ((tloc << 2) + hq) * 68 + (dcq << 2));
                    v += *(const f32x4*)&biasT[h][dcq << 2];
                } else {
                    v = (f32x4){0.f, 0.f, 0.f, 0.f};
                }
                float* dst = batch + ((hd0 + h) * (size_t)Tmax + tglob) * 64;
                *(f32x4*)(dst + (dcq << 2)) = v;
            }
        }
        __syncthreads();
    }
}

// ---------------- fallback path (ws too small) ----------------
__global__ void cums_kernel(const int* __restrict__ mask, int* __restrict__ ws,
                            float* __restrict__ valid_out, int Tmax) {
    int tid = threadIdx.x;
    int w = tid >> 6, lane = tid & 63;
    int m = mask[w * 256 + lane] + mask[w * 256 + lane + 64] +
            mask[w * 256 + lane + 128] + mask[w * 256 + lane + 192];
#pragma unroll
    for (int off = 32; off > 0; off >>= 1) m += __shfl_down(m, off);
    if (lane == 0) ws[w] = m;
    __syncthreads();
    if (tid == 0) {
        for (int b = 0; b < 4; ++b) {
            int c = 0;
            for (int j = 0; j < 4; ++j) { ws[16 + b * 4 + j] = c; c += ws[b * 4 + j]; }
            ws[32 + b] = c;
        }
    }
    __syncthreads();
    for (int i = tid; i < 4 * Tmax; i += 1024) {
        int b = i / Tmax;
        int T = i - b * Tmax;
        valid_out[i] = (T < ws[32 + b]) ? 1.0f : 0.0f;
    }
}

__global__ void pooled_kernel(const float* __restrict__ lh, const int* __restrict__ mask,
                              const int* __restrict__ ws, float* __restrict__ pooled) {
    int bs = blockIdx.x / 12;
    int ec = blockIdx.x - bs * 12;
    int tid = threadIdx.x;
    int tg = tid >> 6, lane = tid & 63;
    int e = ec * 64 + lane;
    float s = 0.f;
    for (int t = tg; t < 256; t += 4) {
        float mf = (float)mask[bs * 256 + t];
        s += lh[(size_t)(bs * 256 + t) * 768 + e] * mf;
    }
    __shared__ float red[4][64];
    red[tg][lane] = s;
    __syncthreads();
    if (tg == 0) {
        float tot = red[0][lane] + red[1][lane] + red[2][lane] + red[3][lane];
        pooled[bs * 768 + e] = tot / (float)ws[bs];
    }
}

__global__ void zerotail_kernel(float* __restrict__ batch, const int* __restrict__ ws,
                                int Tmax) {
    int rr = blockIdx.x;
    int b = rr >> 9;
    int rem = rr & 511;
    int l = rem >> 5, s = (rem >> 4) & 1, h = rem & 15;
    int total = ws[32 + b];
    int span = Tmax - total;
    if (span <= 0) return;
    float* row = batch + (((size_t)((l * 2 + s) * 4 + b) * 16 + h) * (size_t)Tmax + total) * 64;
    f32x4 z = {0.f, 0.f, 0.f, 0.f};
    int nchunk = span << 4;
    for (int j = threadIdx.x; j < nchunk; j += 256)
        *(f32x4*)(row + (j << 2)) = z;
}

__global__ __launch_bounds__(512, 4) void gemm_fb(
    const float* __restrict__ lh, const float* __restrict__ wgt,
    const float* __restrict__ bias, const int* __restrict__ ws,
    float* __restrict__ out, int Tmax) {
    __shared__ __align__(16) unsigned short As[1024][32];
    __shared__ __align__(16) float biasT[16][64];

    int x = blockIdx.x;
    int xcd = x & 7;
    int rest = x >> 3;
    int lsq = rest >> 7;
    int rb = rest & 127;
    int ls = (lsq << 3) + xcd;
    int bs = rb >> 3;
    int tq = rb & 7;

    int len = ws[bs];
    int tbase = tq << 5;
    if (tbase >= len) return;

    int tid = threadIdx.x;
    {
        int i0 = tid, i1 = tid + 512;
        biasT[i0 & 15][((i0 >> 8) << 4) + ((i0 & 255) >> 4)] = bias[(ls << 10) + i0];
        biasT[i1 & 15][((i1 >> 8) << 4) + ((i1 & 255) >> 4)] = bias[(ls << 10) + i1];
    }

    int lane = tid & 63;
    int wv = tid >> 6;
    int beta = wv >> 1, oh = wv & 1;
    int p = lane & 15, q = lane >> 4;

    f32x4 acc[8][2] = {};

#pragma unroll
    for (int cc = 0; cc < 6; ++cc) {
        const int kk = cc << 5;
        const float* Awg = wgt + (size_t)ls * 196608;
        int arow0 = tid >> 2;
        int achk = tid & 3;
#pragma unroll
        for (int it = 0; it < 8; ++it) {
            int row = arow0 + (it << 7);
            const float* src = Awg + row * 192 + kk + (achk << 3);
            f32x4 a0 = *(const f32x4*)src;
            f32x4 a1 = *(const f32x4*)(src + 4);
            u16x8 aw = { f2bf(a0[0]), f2bf(a0[1]), f2bf(a0[2]), f2bf(a0[3]),
                         f2bf(a1[0]), f2bf(a1[1]), f2bf(a1[2]), f2bf(a1[3]) };
            *(u16x8*)&As[row][(achk ^ ((row >> 1) & 3)) << 3] = aw;
        }
        bf16x8 bf[2];
        const float* Brow = lh + (size_t)bs * 196608 + (size_t)(tbase + p) * 768 +
                            beta * 192 + (q << 3) + kk;
#pragma unroll
        for (int n = 0; n < 2; ++n) {
            const float* bp = Brow + n * 16 * 768;
            f32x4 b0 = *(const f32x4*)bp;
            f32x4 b1 = *(const f32x4*)(bp + 4);
            u16x8 bw = { f2bf(b0[0]), f2bf(b0[1]), f2bf(b0[2]), f2bf(b0[3]),
                         f2bf(b1[0]), f2bf(b1[1]), f2bf(b1[2]), f2bf(b1[3]) };
            bf[n] = __builtin_bit_cast(bf16x8, bw);
        }
        __syncthreads();
#pragma unroll
        for (int r8 = 0; r8 < 8; ++r8) {
            int row = (beta << 8) + (oh << 7) + (r8 << 4) + p;
            bf16x8 af = ldfrag(&As[row][(q ^ ((row >> 1) & 3)) << 3]);
            acc[r8][0] = __builtin_amdgcn_mfma_f32_16x16x32_bf16(af, bf[0], acc[r8][0], 0, 0, 0);
            acc[r8][1] = __builtin_amdgcn_mfma_f32_16x16x32_bf16(af, bf[1], acc[r8][1], 0, 0, 0);
        }
        __syncthreads();
    }

    float* Ltr = (float*)&As[0][0];
    int cum = ws[16 + bs];
    int b = bs >> 2;
    float* batch = out + 12288;
    size_t hd0 = (size_t)((ls << 2) + b) << 4;

    int toff = lane & 3, dcq = lane >> 2;
    int col0 = (beta << 4) + (oh << 3);

#pragma unroll
    for (int r = 0; r < 4; ++r) {
#pragma unroll
        for (int n = 0; n < 2; ++n) {
            int rowL = (((n << 4) + p) << 2) + q;
            f32x4 v0 = { acc[0][n][r], acc[1][n][r], acc[2][n][r], acc[3][n][r] };
            f32x4 v1 = { acc[4][n][r], acc[5][n][r], acc[6][n][r], acc[7][n][r] };
            *(f32x4*)(Ltr + rowL * 68 + col0) = v0;
            *(f32x4*)(Ltr + rowL * 68 + col0 + 4) = v1;
        }
        __syncthreads();
#pragma unroll
        for (int gi = 0; gi < 4; ++gi) {
            int flat = (wv << 2) + gi;
            int hq = flat >> 3, t4 = flat & 7;
            int tloc = (t4 << 2) + toff;
            int h = (hq << 2) + r;
            int tglob = tbase + tloc;
            f32x4 v = *(const f32x4*)(Ltr + ((tloc << 2) + hq) * 68 + (dcq << 2));
            v += *(const f32x4*)&biasT[h][dcq << 2];
            if (tglob < len) {
                float* dst = batch + ((hd0 + h) * (size_t)Tmax + cum + tglob) * 64;
                *(f32x4*)(dst + (dcq << 2)) = v;
            }
        }
        __syncthreads();
    }
}

extern "C" void kernel_launch(void* const* d_in, const int* in_sizes, int n_in,
                              void* d_out, int out_size, void* d_ws, size_t ws_size,
                              hipStream_t stream) {
    const float* lh   = (const float*)d_in[0];
    const int*   mask = (const int*)d_in[1];
    const float* wgt  = (const float*)d_in[2];
    const float* bias = (const float*)d_in[3];
    float* out = (float*)d_out;
    int* ws = (int*)d_ws;

    int Tmax = (out_size - 12288) / 131076;
    int nT = (Tmax + 31) >> 5;

    unsigned short* Wp = (unsigned short*)((char*)d_ws + 1024);
    unsigned short* Lp = (unsigned short*)((char*)d_ws + 1024 + 12582912);
    const size_t need = 1024 + 12582912 + 6291456;
    bool packed = ws_size >= need;

    float* valid_out = out + 12288 + (size_t)131072 * Tmax;

    if (packed) {
        prep_kernel<<<4801, 256, 0, stream>>>(wgt, lh, mask, Wp, Lp, ws, out, valid_out, Tmax);
        gemm_t<<<128 * nT, 512, 0, stream>>>(Wp, Lp, bias, ws, out, Tmax, nT);
    } else {
        cums_kernel<<<1, 1024, 0, stream>>>(mask, ws, valid_out, Tmax);
        pooled_kernel<<<16 * 12, 256, 0, stream>>>(lh, mask, ws, out);
        zerotail_kernel<<<2048, 256, 0, stream>>>(out + 12288, ws, Tmax);
        gemm_fb<<<4096, 512, 0, stream>>>(lh, wgt, bias, ws, out, Tmax);
    }
}